// Round 5
// baseline (2340.314 us; speedup 1.0000x reference)
//
#include <hip/hip_runtime.h>
#include <math.h>

#define DEV __device__ __forceinline__

// ---------------- problem dims ----------------
static constexpr int BB   = 128;     // batch
static constexpr int NN   = 300;     // tgt & memory seq len
static constexpr int DM   = 512;     // d_model

typedef __attribute__((ext_vector_type(8))) short short8;   // 8 bf16 = 4 VGPR
typedef __attribute__((ext_vector_type(4))) float f32x4;

// ---------------- helpers ----------------
DEV unsigned short f2bf(float f) {
  unsigned u = __float_as_uint(f);
  unsigned r = (u + 0x7fffu + ((u >> 16) & 1u)) >> 16;
  return (unsigned short)r;
}
DEV float bf2f(unsigned short s) { return __uint_as_float((unsigned)s << 16); }
DEV unsigned pack_trunc(float a, float b) {   // truncate-to-bf16 pack (P in [0,1])
  return (__float_as_uint(a) >> 16) | (__float_as_uint(b) & 0xffff0000u);
}

// async global(16B/lane) -> LDS (wave-uniform base + lane*16)
DEV void gld16(const void* g, void* l) {
  __builtin_amdgcn_global_load_lds(
      (const __attribute__((address_space(1))) unsigned int*)g,
      (__attribute__((address_space(3))) unsigned int*)l,
      16, 0, 0);
}

// =================== LayerNorm (one wave per row of 512) -> bf16 out ===================
__global__ __launch_bounds__(256) void ln_kernel(
    const float* __restrict__ X, const float* __restrict__ g,
    const float* __restrict__ b, unsigned short* __restrict__ Y, int rows)
{
  int wv = threadIdx.x >> 6, lane = threadIdx.x & 63;
  int row = blockIdx.x * 4 + wv;
  if (row >= rows) return;
  const float* xp = X + (size_t)row * DM;
  float v[8]; float s = 0.f, s2 = 0.f;
#pragma unroll
  for (int j = 0; j < 8; j++) {
    v[j] = xp[lane + 64 * j]; s += v[j]; s2 += v[j] * v[j];
  }
#pragma unroll
  for (int o = 32; o >= 1; o >>= 1) { s += __shfl_xor(s, o); s2 += __shfl_xor(s2, o); }
  float mean = s * (1.f / 512.f);
  float var  = s2 * (1.f / 512.f) - mean * mean;
  float rstd = rsqrtf(var + 1e-5f);
  unsigned short* yp = Y + (size_t)row * DM;
#pragma unroll
  for (int j = 0; j < 8; j++) {
    int c = lane + 64 * j;
    yp[c] = f2bf((v[j] - mean) * rstd * g[c] + b[c]);
  }
}

// =================== fused X += (Hw+1)Y + Hb  ->  LN -> bf16 ===================
__global__ __launch_bounds__(256) void align_ln(
    float* __restrict__ X, const float* __restrict__ Y,
    const float* __restrict__ H,
    const float* __restrict__ g, const float* __restrict__ bb,
    unsigned short* __restrict__ XN)
{
  int wv = threadIdx.x >> 6, lane = threadIdx.x & 63;
  int row = blockIdx.x * 4 + wv;
  int b = row / NN;
  float* xp = X + (size_t)row * DM;
  const float* yp = Y + (size_t)row * DM;
  const float* hw = H + (size_t)b * 1024;
  const float* hb = hw + 512;
  float v[8]; float s = 0.f, s2 = 0.f;
#pragma unroll
  for (int j = 0; j < 8; j++) {
    int c = lane + 64 * j;
    float xv = xp[c] + (hw[c] + 1.f) * yp[c] + hb[c];
    v[j] = xv; s += xv; s2 += xv * xv;
  }
#pragma unroll
  for (int j = 0; j < 8; j++) xp[lane + 64 * j] = v[j];
#pragma unroll
  for (int o = 32; o >= 1; o >>= 1) { s += __shfl_xor(s, o); s2 += __shfl_xor(s2, o); }
  float mean = s * (1.f / 512.f);
  float var  = s2 * (1.f / 512.f) - mean * mean;
  float rstd = rsqrtf(var + 1e-5f);
  unsigned short* yn = XN + (size_t)row * DM;
#pragma unroll
  for (int j = 0; j < 8; j++) {
    int c = lane + 64 * j;
    yn[c] = f2bf((v[j] - mean) * rstd * g[c] + bb[c]);
  }
}

// =================== f32 -> bf16 elementwise (weights / memory) ===================
__global__ __launch_bounds__(256) void cvt_bf16(
    const float* __restrict__ in, unsigned short* __restrict__ out, int n4)
{
  int i = blockIdx.x * 256 + threadIdx.x;
  if (i >= n4) return;
  float4 v = ((const float4*)in)[i];
  union { unsigned short s[4]; uint2 u; } o;
  o.s[0] = f2bf(v.x); o.s[1] = f2bf(v.y); o.s[2] = f2bf(v.z); o.s[3] = f2bf(v.w);
  *(uint2*)&out[(size_t)i * 4] = o.u;
}

// =================== f32 [R,C] -> bf16 [R,Cpad], pad cols zero ===================
__global__ __launch_bounds__(256) void cvt_pad_bf16(
    const float* __restrict__ in, unsigned short* __restrict__ out,
    int R, int C, int Cpad)
{
  int idx = blockIdx.x * 256 + threadIdx.x;
  int r = idx / Cpad, c = idx % Cpad;
  if (r >= R) return;
  out[idx] = (c < C) ? f2bf(in[(size_t)r * C + c]) : (unsigned short)0;
}

// =================== transpose f32 [R,C] -> bf16 [Cpad,R], pad rows zero ===================
__global__ __launch_bounds__(256) void transpose_bf16(
    const float* __restrict__ in, unsigned short* __restrict__ out,
    int R, int Ccols, int Cpad)
{
  __shared__ float t[32][33];
  int c0 = blockIdx.x * 32, r0 = blockIdx.y * 32;
  int x = threadIdx.x & 31, y = threadIdx.x >> 5;   // y in 0..7
#pragma unroll
  for (int dy = 0; dy < 32; dy += 8) {
    int r = r0 + y + dy, c = c0 + x;
    t[y + dy][x] = (r < R && c < Ccols) ? in[(size_t)r * Ccols + c] : 0.f;
  }
  __syncthreads();
#pragma unroll
  for (int dy = 0; dy < 32; dy += 8) {
    int c = c0 + y + dy, r = r0 + x;
    if (c < Cpad && r < R) out[(size_t)c * R + r] = f2bf(t[x][y + dy]);
  }
}

// =================== bf16-input GEMM, m97 structure + XCD swizzle ===================
// A bf16 [M,K] k-major, W bf16 [Npad,K] k-major (Npad mult of 128, pad rows zero).
// EPI: 0 f32, 1 f32+bias, 2 bf16 relu(+bias), 3 f32+bias+R,
//      7 bf16+bias head-major QKV planes [sec*8+h][M][64] (uses coloff),
//      8 dual bf16: col<1248 -> Cv [M][1248]; col>=1280 -> R as ushort* [M][640]
template<int EPI>
__global__ __launch_bounds__(256) void gemm_bb(
    const unsigned short* __restrict__ A, int lda,
    const unsigned short* __restrict__ W, int ldw,
    const float* __restrict__ bias,
    const float* __restrict__ R, int ldr,
    void* __restrict__ Cv, int ldc,
    int M, int K, int NC, int coloff)
{
  __shared__ __align__(16) unsigned short As[128 * 32];
  __shared__ __align__(16) unsigned short Bs[128 * 32];
  const int tid = threadIdx.x;
  const int wave = tid >> 6, lane = tid & 63;
  const int wr = wave >> 1, wc = wave & 1;
  const int quad = lane >> 4, l16 = lane & 15;

  // XCD-aware bijective remap (m204): contiguous tile chunk per XCD.
  const unsigned nx = gridDim.x, nwg = nx * gridDim.y;
  const unsigned orig = blockIdx.y * nx + blockIdx.x;
  const unsigned qq = nwg >> 3, rr = nwg & 7;
  const unsigned xcd = orig & 7, idx = orig >> 3;
  const unsigned swz = (xcd < rr) ? (xcd * (qq + 1) + idx)
                                  : (rr * (qq + 1) + (xcd - rr) * qq + idx);
  const int n0 = (int)(swz % nx) * 128;
  const int m0 = (int)(swz / nx) * 128;

  int ra = m0 + (tid >> 2);
  int ra0 = (ra      >= M) ? M - 1 : ra;
  int ra1 = (ra + 64 >= M) ? M - 1 : ra + 64;
  const unsigned short* a0 = A + (size_t)ra0 * lda + (tid & 3) * 8;
  const unsigned short* a1 = A + (size_t)ra1 * lda + (tid & 3) * 8;
  const unsigned short* b0 = W + (size_t)(n0 + (tid >> 2)) * ldw + (tid & 3) * 8;
  const unsigned short* b1 = b0 + (size_t)64 * ldw;
  unsigned short* dA0 = &As[wave * 512];           // issue0: bytes wave*1024
  unsigned short* dA1 = &As[2048 + wave * 512];    // issue1: +4096B
  unsigned short* dB0 = &Bs[wave * 512];
  unsigned short* dB1 = &Bs[2048 + wave * 512];

  f32x4 acc[4][4];
#pragma unroll
  for (int i = 0; i < 4; i++)
#pragma unroll
    for (int j = 0; j < 4; j++) acc[i][j] = (f32x4){0.f, 0.f, 0.f, 0.f};

  for (int k0 = 0; k0 < K; k0 += 32) {
    gld16(a0 + k0, dA0);
    gld16(a1 + k0, dA1);
    gld16(b0 + k0, dB0);
    gld16(b1 + k0, dB1);
    __syncthreads();                 // drains vmcnt -> LDS tiles complete
    short8 af[4], bq[4];
#pragma unroll
    for (int i = 0; i < 4; i++)
      af[i] = *(const short8*)&As[(wr * 64 + i * 16 + l16) * 32 + quad * 8];
#pragma unroll
    for (int j = 0; j < 4; j++)
      bq[j] = *(const short8*)&Bs[(wc * 64 + j * 16 + l16) * 32 + quad * 8];
#pragma unroll
    for (int i = 0; i < 4; i++)
#pragma unroll
      for (int j = 0; j < 4; j++)
        acc[i][j] = __builtin_amdgcn_mfma_f32_16x16x32_bf16(af[i], bq[j], acc[i][j], 0, 0, 0);
    __syncthreads();                 // all reads done before next overwrite
  }

#pragma unroll
  for (int i = 0; i < 4; i++) {
    int rbase = m0 + wr * 64 + i * 16 + quad * 4;
#pragma unroll
    for (int r = 0; r < 4; r++) {
      int row = rbase + r;
      if (row < M) {
        size_t rowc = (size_t)row * ldc;
#pragma unroll
        for (int j = 0; j < 4; j++) {
          int col = n0 + wc * 64 + j * 16 + l16;
          if (col < NC) {
            float e = acc[i][j][r];
            if (EPI == 1 || EPI == 2 || EPI == 3 || EPI == 7) e += bias[col];
            if (EPI == 3) e += R[(size_t)row * ldr + col];
            if (EPI == 2) {
              ((unsigned short*)Cv)[rowc + col] = f2bf(fmaxf(e, 0.f));
            } else if (EPI == 7) {
              int cc = col + coloff;
              int sec = cc >> 9, hh = (cc >> 6) & 7, dh = cc & 63;
              ((unsigned short*)Cv)[(((size_t)(sec * 8 + hh)) * M + row) * 64 + dh] = f2bf(e);
            } else if (EPI == 8) {
              if (col < 1248)
                ((unsigned short*)Cv)[(size_t)row * 1248 + col] = f2bf(e);
              else if (col >= 1280)
                ((unsigned short*)(void*)R)[(size_t)row * 640 + (col - 1280)] = f2bf(e);
            } else {
              ((float*)Cv)[rowc + col] = e;
            }
          }
        }
      }
    }
  }
}

// =================== ds (kinematic-tree) attention, bf16 COMB + bf16 V ===================
__global__ __launch_bounds__(256) void ds_attn_kernel(
    const unsigned short* __restrict__ COMB, unsigned short* __restrict__ V)
{
  __shared__ float ks[4][2][24][6];
  __shared__ float vs[4][2][24][6];
  int wv = threadIdx.x >> 6, lane = threadIdx.x & 63;
  int half = lane >> 5, i = lane & 31;
  int u  = blockIdx.x * 4 + wv;     // head-pair unit
  int bn = u >> 1, hp = u & 1;
  int h  = hp * 2 + half;
  size_t cbase = (size_t)bn * 1248 + h * 156 + 3;
  size_t vbase = (size_t)bn * 640  + h * 156 + 3;

  float q[6];
  if (i < 24) {
#pragma unroll
    for (int j = 0; j < 6; j++) {
      q[j]                 = bf2f(COMB[cbase + i * 6 + j]);
      ks[wv][half][i][j]   = bf2f(COMB[cbase + 624 + i * 6 + j]);
      vs[wv][half][i][j]   = bf2f(V[vbase + i * 6 + j]);
    }
  } else {
#pragma unroll
    for (int j = 0; j < 6; j++) q[j] = 0.f;
  }
  __syncthreads();

  float p[24];
#pragma unroll
  for (int k = 0; k < 24; k++) p[k] = 0.f;

  if (i < 24) {
    float mx = -1e30f;
#pragma unroll
    for (int k = 0; k < 24; k++) {
      float s = 0.f;
#pragma unroll
      for (int j = 0; j < 6; j++) s += q[j] * ks[wv][half][k][j];
      s *= 0.4082482904638631f;   // 1/sqrt(6)
      p[k] = s; mx = fmaxf(mx, s);
    }
    float sum = 0.f;
#pragma unroll
    for (int k = 0; k < 24; k++) { p[k] = __expf(p[k] - mx); sum += p[k]; }
    float inv = 1.f / sum;
#pragma unroll
    for (int k = 0; k < 24; k++) p[k] *= inv;
  }

  {
    float c = p[0];
    float t;
    t = __shfl(c, 3, 32);  if (i == 6) c = (c + t) * 0.5f;
    t = __shfl(c, 6, 32);  if (i == 9) c = (c + t) * 0.5f;
    t = __shfl(c, 9, 32);  if (i >= 12 && i <= 14) c = (c + t) * 0.5f;
    int src = (i >= 3) ? (i - 3) : 0;
    t = __shfl(c, src, 32); if (i >= 15 && i <= 17) c = (c + t) * 0.5f;
    p[0] = c;
  }
  if (i == 0) {
    p[6]  = (p[6]  + p[3])  * 0.5f;
    p[9]  = (p[9]  + p[6])  * 0.5f;
    p[12] = (p[12] + p[9])  * 0.5f;
    p[13] = (p[13] + p[9])  * 0.5f;
    p[14] = (p[14] + p[9])  * 0.5f;
    p[16] = (p[16] + p[13]) * 0.5f;
    p[17] = (p[17] + p[14]) * 0.5f;
    p[15] = (p[15] + p[12]) * 0.5f;
  }

  if (i < 24) {
    float o[6] = {0.f, 0.f, 0.f, 0.f, 0.f, 0.f};
#pragma unroll
    for (int k = 0; k < 24; k++) {
#pragma unroll
      for (int j = 0; j < 6; j++) o[j] += p[k] * vs[wv][half][k][j];
    }
#pragma unroll
    for (int j = 0; j < 6; j++) V[vbase + i * 6 + j] = f2bf(o[j]);
  }
}

// =================== MFMA MHA, head-major QKV planes [sec*8+h][rowsT][64] ===================
// Each block streams contiguous K/V/Q planes; O via per-wave LDS transpose.
__global__ __launch_bounds__(512) void mha_mfma(
    const unsigned short* __restrict__ QKV3, unsigned short* __restrict__ Op,
    int rowsT, float scale)
{
  __shared__ __align__(16) unsigned short Ksh[304 * 72];
  __shared__ __align__(16) unsigned short Vt[64 * 328];
  __shared__ __align__(16) unsigned short Pt[8][16 * 68];
  const int bh = blockIdx.x, b = bh >> 3, h = bh & 7;
  const int tid = threadIdx.x, wv = tid >> 6, lane = tid & 63;
  const int quad = lane >> 4, l16 = lane & 15;
  const unsigned short* Qp = QKV3 + ((size_t)h        * rowsT + b * NN) * 64;
  const unsigned short* Kp = QKV3 + ((size_t)(8 + h)  * rowsT + b * NN) * 64;
  const unsigned short* Vp = QKV3 + ((size_t)(16 + h) * rowsT + b * NN) * 64;

  // ---- stage K: contiguous [300][64] -> Ksh[304][72] (rows 300..303 zero) ----
  for (int f = tid; f < 304 * 8; f += 512) {
    int rk = f >> 3, c8 = (f & 7) * 8;
    short8 w;
    if (rk < 300) {
      w = *(const short8*)(Kp + f * 8);          // rk*64 + c8 == f*8
    } else {
      union { uint4 u; short8 s; } z; z.u = make_uint4(0u, 0u, 0u, 0u); w = z.s;
    }
    *(short8*)&Ksh[rk * 72 + c8] = w;
  }
  // ---- stage V^T: Vt[d][seq], seq >= 300 zeroed ----
  for (int f = tid; f < 64 * 164; f += 512) {
    int d = f & 63, s0 = (f >> 6) * 2;
    unsigned w = 0u;
    if (s0 < 300) {
      unsigned short v0 = Vp[s0 * 64 + d];
      unsigned short v1 = (s0 + 1 < 300) ? Vp[(s0 + 1) * 64 + d] : (unsigned short)0;
      w = (unsigned)v0 | ((unsigned)v1 << 16);
    }
    *(unsigned*)&Vt[d * 328 + s0] = w;
  }
  __syncthreads();

  unsigned short* pt = &Pt[wv][0];

  for (int qt = wv; qt < 19; qt += 8) {
    int qr = qt * 16 + l16; if (qr > 299) qr = 299;   // clamp; dup cols unused
    short8 qf[2];
    qf[0] = *(const short8*)(Qp + qr * 64 + quad * 8);
    qf[1] = *(const short8*)(Qp + qr * 64 + 32 + quad * 8);

    // S' = K Q^T: rows = seq (19 tiles of 16), cols = qrow
    f32x4 sacc[19];
#pragma unroll
    for (int t = 0; t < 19; t++) {
      short8 k0 = *(const short8*)&Ksh[(t * 16 + l16) * 72 + quad * 8];
      short8 k1 = *(const short8*)&Ksh[(t * 16 + l16) * 72 + 32 + quad * 8];
      f32x4 a = (f32x4){0.f, 0.f, 0.f, 0.f};
      a = __builtin_amdgcn_mfma_f32_16x16x32_bf16(k0, qf[0], a, 0, 0, 0);
      a = __builtin_amdgcn_mfma_f32_16x16x32_bf16(k1, qf[1], a, 0, 0, 0);
      sacc[t] = a;
    }

    // softmax over seq for qrow = l16: in-lane over (t,r), cross-quad shfl
    float mx = -1e30f;
#pragma unroll
    for (int t = 0; t < 19; t++)
#pragma unroll
      for (int r = 0; r < 4; r++) mx = fmaxf(mx, sacc[t][r]);
    mx = fmaxf(mx, __shfl_xor(mx, 16));
    mx = fmaxf(mx, __shfl_xor(mx, 32));
    float sum = 0.f;
#pragma unroll
    for (int t = 0; t < 19; t++) {
#pragma unroll
      for (int r = 0; r < 4; r++) {
        float p = __expf((sacc[t][r] - mx) * scale);
        if (t == 18 && quad == 3) p = 0.f;     // seq 300..303 pad
        sacc[t][r] = p; sum += p;
      }
    }
    sum += __shfl_xor(sum, 16);
    sum += __shfl_xor(sum, 32);
    float inv = 1.f / sum;

    // PV: O[qrow][d] = sum_seq P[seq][qrow] V[seq][d]
    f32x4 oacc[4];
#pragma unroll
    for (int dt = 0; dt < 4; dt++) oacc[dt] = (f32x4){0.f, 0.f, 0.f, 0.f};
#pragma unroll
    for (int c = 0; c < 10; c++) {
#pragma unroll
      for (int tic = 0; tic < 2; tic++) {
        int t = 2 * c + tic;
        unsigned w0 = 0u, w1 = 0u;
        if (t < 19) {
          w0 = pack_trunc(sacc[t][0], sacc[t][1]);
          w1 = pack_trunc(sacc[t][2], sacc[t][3]);
        }
        *(unsigned*)&pt[l16 * 68 + tic * 16 + quad * 4]     = w0;
        *(unsigned*)&pt[l16 * 68 + tic * 16 + quad * 4 + 2] = w1;
      }
      short8 pa = *(const short8*)&pt[l16 * 68 + quad * 8];
#pragma unroll
      for (int dt = 0; dt < 4; dt++) {
        short8 vb = *(const short8*)&Vt[(dt * 16 + l16) * 328 + c * 32 + quad * 8];
        oacc[dt] = __builtin_amdgcn_mfma_f32_16x16x32_bf16(pa, vb, oacc[dt], 0, 0, 0);
      }
    }

    // epilogue: transpose through Pt, then 16B/lane contiguous stores
#pragma unroll
    for (int r = 0; r < 4; r++) {
      float iv = __shfl(inv, quad * 4 + r);
#pragma unroll
      for (int dt = 0; dt < 4; dt++)
        pt[(quad * 4 + r) * 68 + dt * 16 + l16] = f2bf(oacc[dt][r] * iv);
    }
#pragma unroll
    for (int rep = 0; rep < 2; rep++) {
      int idx = rep * 64 + lane;
      int rl = idx >> 3, seg = idx & 7;
      int row = qt * 16 + rl;
      uint4 w = *(const uint4*)&pt[rl * 68 + seg * 8];
      if (row < 300)
        *(uint4*)(Op + (size_t)(b * NN + row) * DM + h * 64 + seg * 8) = w;
    }
  }
}

// =================== column mean over seq + mish(t + mean) -> bf16 ===================
__global__ __launch_bounds__(256) void colmean_mish(
    const float* __restrict__ Y, const float* __restrict__ tvec,
    unsigned short* __restrict__ mm)
{
  int g = blockIdx.x * 256 + threadIdx.x;
  int b = g >> 9, d = g & 511;
  const float* yp = Y + (size_t)b * NN * DM + d;
  float s = 0.f;
  for (int n = 0; n < NN; n++) s += yp[(size_t)n * DM];
  float v = tvec[g] + s * (1.f / 300.f);
  float sp = (v > 20.f) ? v : log1pf(__expf(v));
  mm[g] = f2bf(v * tanhf(sp));
}

// =================== X += (Hw+1)*Y + Hb ===================
__global__ __launch_bounds__(256) void align_apply(
    float* __restrict__ X, const float* __restrict__ Y,
    const float* __restrict__ H)
{
  int idx = blockIdx.x * 256 + threadIdx.x;  // rows*128 float4s
  int row = idx >> 7;
  int d4  = (idx & 127) * 4;
  int b   = row / NN;
  float4 y = *(const float4*)&Y[(size_t)row * DM + d4];
  float4 x = *(const float4*)&X[(size_t)row * DM + d4];
  const float* hw = H + (size_t)b * 1024 + d4;
  const float* hb = hw + 512;
  x.x += (hw[0] + 1.f) * y.x + hb[0];
  x.y += (hw[1] + 1.f) * y.y + hb[1];
  x.z += (hw[2] + 1.f) * y.z + hb[2];
  x.w += (hw[3] + 1.f) * y.w + hb[3];
  *(float4*)&X[(size_t)row * DM + d4] = x;
}

// =================== launch ===================
extern "C" void kernel_launch(void* const* d_in, const int* in_sizes, int n_in,
                              void* d_out, int out_size, void* d_ws, size_t ws_size,
                              hipStream_t stream)
{
  const float* tgt      = (const float*)d_in[0];
  const float* memory   = (const float*)d_in[1];
  const float* tvec     = (const float*)d_in[2];
  const float* qk_w     = (const float*)d_in[3];
  const float* v_w      = (const float*)d_in[4];
  const float* ds_lw    = (const float*)d_in[5];
  const float* ds_lb    = (const float*)d_in[6];
  const float* ta_in_w  = (const float*)d_in[7];
  const float* ta_in_b  = (const float*)d_in[8];
  const float* ta_out_w = (const float*)d_in[9];
  const float* ta_out_b = (const float*)d_in[10];
  const float* ca_in_w  = (const float*)d_in[11];
  const float* ca_in_b  = (const float*)d_in[12];
  const float* ca_out_w = (const float*)d_in[13];
  const float* ca_out_b = (const float*)d_in[14];
  const float* l1_w     = (const float*)d_in[15];
  const float* l1_b     = (const float*)d_in[16];
  const float* l2_w     = (const float*)d_in[17];
  const float* l2_b     = (const float*)d_in[18];
  const float* n1_g = (const float*)d_in[19]; const float* n1_b = (const float*)d_in[20];
  const float* n2_g = (const float*)d_in[21]; const float* n2_b = (const float*)d_in[22];
  const float* n3_g = (const float*)d_in[23]; const float* n3_b = (const float*)d_in[24];
  const float* n4_g = (const float*)d_in[25]; const float* n4_b = (const float*)d_in[26];
  const float* a1_w = (const float*)d_in[27]; const float* a1_b = (const float*)d_in[28];
  const float* a2_w = (const float*)d_in[29]; const float* a2_b = (const float*)d_in[30];
  const float* a3_w = (const float*)d_in[31]; const float* a3_b = (const float*)d_in[32];

  // ---- fixed workspace (bytes): bf16 weight copies ----
  const size_t W_W2  = 1920ULL * 512 * 2;    // merged qk^T (1280) + v^T (640)
  const size_t W_TAI = 1536ULL * 512 * 2;
  const size_t W_TAO = 512ULL  * 512 * 2;
  const size_t W_CAI = 1536ULL * 512 * 2;
  const size_t W_CAO = 512ULL  * 512 * 2;
  const size_t W_L1  = 2048ULL * 512 * 2;
  const size_t W_L2  = 512ULL  * 2048 * 2;
  const size_t W_DSL = 512ULL  * 640 * 2;
  const size_t W_AX  = 1024ULL * 512 * 2;    // x3
  const size_t W_MEM = (size_t)BB * NN * 512 * 2;
  const size_t fixedB = W_W2 + W_TAI + W_TAO + W_CAI + W_CAO
                      + W_L1 + W_L2 + W_DSL + 3 * W_AX + W_MEM;
  // per-batch: XNh bf16[300][512] + SCRB 300x4096B (COMB bf16 1248 / QKV3 planes
  // 1536x2B / FFN bf16 2048) + Vdsh bf16[300][640] + Yb f32[300][512] + MMh + Hb
  const size_t per_b = 300ULL * (1024 + 4096 + 1280 + 2048) + 1024 + 4096;  // 2,539,520
  int Bc = 128;
  while (Bc > 16 && fixedB + (size_t)Bc * per_b > ws_size) Bc >>= 1;
  const int rows = Bc * NN;
  const int mB   = (rows + 127) / 128;
  const int aB   = (Bc + 127) / 128;
  const int nchunks = BB / Bc;

  char* p = (char*)d_ws;
  unsigned short* W2h   = (unsigned short*)p; p += W_W2;
  unsigned short* taiWh = (unsigned short*)p; p += W_TAI;
  unsigned short* taoWh = (unsigned short*)p; p += W_TAO;
  unsigned short* caiWh = (unsigned short*)p; p += W_CAI;
  unsigned short* caoWh = (unsigned short*)p; p += W_CAO;
  unsigned short* l1Wh  = (unsigned short*)p; p += W_L1;
  unsigned short* l2Wh  = (unsigned short*)p; p += W_L2;
  unsigned short* dslWh = (unsigned short*)p; p += W_DSL;
  unsigned short* a1Wh  = (unsigned short*)p; p += W_AX;
  unsigned short* a2Wh  = (unsigned short*)p; p += W_AX;
  unsigned short* a3Wh  = (unsigned short*)p; p += W_AX;
  unsigned short* memh  = (unsigned short*)p; p += W_MEM;
  unsigned short* XNh   = (unsigned short*)p; p += (size_t)rows * 512 * 2;
  char* SCRB = p;                             p += (size_t)rows * 4096;
  unsigned short* Vdsh  = (unsigned short*)p; p += (size_t)rows * 640 * 2;
  float* Yb  = (float*)p; p += (size_t)rows * 512 * 4;
  unsigned short* MMh = (unsigned short*)p;   p += (size_t)Bc * 512 * 2;
  float* Hb  = (float*)p;

  unsigned short* COMBh = (unsigned short*)SCRB; // [rows][1248] bf16
  unsigned short* QKV3  = (unsigned short*)SCRB; // [24][rows][64] bf16 planes
  unsigned short* T2h   = (unsigned short*)SCRB; // [rows][2048] bf16

  dim3 thr(256);

  // ---- one-time weight / memory conversion ----
  transpose_bf16<<<dim3(40, 16), thr, 0, stream>>>(qk_w, W2h, 512, 1248, 1280);
  transpose_bf16<<<dim3(20, 16), thr, 0, stream>>>(v_w,  W2h + 1280 * 512, 512, 624, 640);
  cvt_pad_bf16<<<dim3(512 * 640 / 256), thr, 0, stream>>>(ds_lw, dslWh, 512, 624, 640);
  auto cvt = [&](const float* src, unsigned short* dst, size_t n) {
    int n4 = (int)(n / 4);
    cvt_bf16<<<dim3((n4 + 255) / 256), thr, 0, stream>>>(src, dst, n4);
  };
  cvt(ta_in_w,  taiWh, 1536ULL * 512);
  cvt(ta_out_w, taoWh, 512ULL * 512);
  cvt(ca_in_w,  caiWh, 1536ULL * 512);
  cvt(ca_out_w, caoWh, 512ULL * 512);
  cvt(l1_w,     l1Wh,  2048ULL * 512);
  cvt(l2_w,     l2Wh,  512ULL * 2048);
  cvt(a1_w,     a1Wh,  1024ULL * 512);
  cvt(a2_w,     a2Wh,  1024ULL * 512);
  cvt(a3_w,     a3Wh,  1024ULL * 512);
  cvt(memory,   memh,  (size_t)BB * NN * 512);

  for (int c = 0; c < nchunks; ++c) {
    const size_t roff = (size_t)c * Bc * NN * DM;
    const float* tgtC = tgt    + roff;
    const float* tC   = tvec   + (size_t)c * Bc * 512;
    const unsigned short* memhC = memh + roff;
    float*       XC   = (float*)d_out + roff;

    // ---- ds-attention branch: x = tgt + ds_attn(LN1(tgt)) ----
    ln_kernel<<<rows / 4, thr, 0, stream>>>(tgtC, n1_g, n1_b, XNh, rows);
    gemm_bb<8><<<dim3(15, mB), thr, 0, stream>>>(XNh, 512, W2h, 512, nullptr, (const float*)Vdsh, 0, COMBh, 1248, rows, 512, 1920, 0);
    ds_attn_kernel<<<rows / 2, thr, 0, stream>>>(COMBh, Vdsh);
    gemm_bb<3><<<dim3(4, mB),  thr, 0, stream>>>(Vdsh, 640, dslWh, 640, ds_lb, tgtC, 512, XC, 512, rows, 640, 512, 0);

    // ---- self attention + align1 (+fused LN3) ----
    ln_kernel<<<rows / 4, thr, 0, stream>>>(XC, n2_g, n2_b, XNh, rows);
    gemm_bb<7><<<dim3(12, mB), thr, 0, stream>>>(XNh, 512, taiWh, 512, ta_in_b, nullptr, 0, QKV3, 0, rows, 512, 1536, 0);
    mha_mfma<<<Bc * 8, 512, 0, stream>>>(QKV3, XNh, rows, 0.125f);
    gemm_bb<1><<<dim3(4, mB),  thr, 0, stream>>>(XNh, 512, taoWh, 512, ta_out_b, nullptr, 0, Yb, 512, rows, 512, 512, 0);
    colmean_mish<<<Bc * 2, thr, 0, stream>>>(Yb, tC, MMh);
    gemm_bb<1><<<dim3(8, aB),  thr, 0, stream>>>(MMh, 512, a1Wh, 512, a1_b, nullptr, 0, Hb, 1024, Bc, 512, 1024, 0);
    align_ln<<<rows / 4, thr, 0, stream>>>(XC, Yb, Hb, n3_g, n3_b, XNh);

    // ---- cross attention + align2 (+fused LN4) ----
    gemm_bb<7><<<dim3(4, mB),  thr, 0, stream>>>(XNh, 512, caiWh, 512, ca_in_b, nullptr, 0, QKV3, 0, rows, 512, 512, 0);
    gemm_bb<7><<<dim3(8, mB),  thr, 0, stream>>>(memhC, 512, caiWh + 512 * 512, 512, ca_in_b + 512, nullptr, 0, QKV3, 0, rows, 512, 1024, 512);
    mha_mfma<<<Bc * 8, 512, 0, stream>>>(QKV3, XNh, rows, 0.125f);
    gemm_bb<1><<<dim3(4, mB),  thr, 0, stream>>>(XNh, 512, caoWh, 512, ca_out_b, nullptr, 0, Yb, 512, rows, 512, 512, 0);
    colmean_mish<<<Bc * 2, thr, 0, stream>>>(Yb, tC, MMh);
    gemm_bb<1><<<dim3(8, aB),  thr, 0, stream>>>(MMh, 512, a2Wh, 512, a2_b, nullptr, 0, Hb, 1024, Bc, 512, 1024, 0);
    align_ln<<<rows / 4, thr, 0, stream>>>(XC, Yb, Hb, n4_g, n4_b, XNh);

    // ---- FFN (merged N=2048, K=2048) + align3 ----
    gemm_bb<2><<<dim3(16, mB), thr, 0, stream>>>(XNh, 512, l1Wh, 512, l1_b, nullptr, 0, T2h, 2048, rows, 512, 2048, 0);
    gemm_bb<1><<<dim3(4, mB),  thr, 0, stream>>>(T2h, 2048, l2Wh, 2048, l2_b, nullptr, 0, Yb, 512, rows, 2048, 512, 0);
    colmean_mish<<<Bc * 2, thr, 0, stream>>>(Yb, tC, MMh);
    gemm_bb<1><<<dim3(8, aB),  thr, 0, stream>>>(MMh, 512, a3Wh, 512, a3_b, nullptr, 0, Hb, 1024, Bc, 512, 1024, 0);
    align_apply<<<rows / 2, thr, 0, stream>>>(XC, Yb, Hb);
  }
}

// Round 6
// 1926.320 us; speedup vs baseline: 1.2149x; 1.2149x over previous
//
#include <hip/hip_runtime.h>
#include <math.h>

#define DEV __device__ __forceinline__

// ---------------- problem dims ----------------
static constexpr int BB   = 128;     // batch
static constexpr int NN   = 300;     // tgt & memory seq len
static constexpr int DM   = 512;     // d_model

typedef __attribute__((ext_vector_type(8))) short short8;   // 8 bf16 = 4 VGPR
typedef __attribute__((ext_vector_type(4))) float f32x4;

// ---------------- helpers ----------------
DEV unsigned short f2bf(float f) {
  unsigned u = __float_as_uint(f);
  unsigned r = (u + 0x7fffu + ((u >> 16) & 1u)) >> 16;
  return (unsigned short)r;
}
DEV float bf2f(unsigned short s) { return __uint_as_float((unsigned)s << 16); }
DEV unsigned pack_trunc(float a, float b) {   // truncate-to-bf16 pack (P in [0,1])
  return (__float_as_uint(a) >> 16) | (__float_as_uint(b) & 0xffff0000u);
}

// async global(16B/lane) -> LDS (wave-uniform base + lane*16)
DEV void gld16(const void* g, void* l) {
  __builtin_amdgcn_global_load_lds(
      (const __attribute__((address_space(1))) unsigned int*)g,
      (__attribute__((address_space(3))) unsigned int*)l,
      16, 0, 0);
}

// =================== LayerNorm (one wave per row of 512) -> bf16 out ===================
__global__ __launch_bounds__(256) void ln_kernel(
    const float* __restrict__ X, const float* __restrict__ g,
    const float* __restrict__ b, unsigned short* __restrict__ Y, int rows)
{
  int wv = threadIdx.x >> 6, lane = threadIdx.x & 63;
  int row = blockIdx.x * 4 + wv;
  if (row >= rows) return;
  const float* xp = X + (size_t)row * DM;
  float v[8]; float s = 0.f, s2 = 0.f;
#pragma unroll
  for (int j = 0; j < 8; j++) {
    v[j] = xp[lane + 64 * j]; s += v[j]; s2 += v[j] * v[j];
  }
#pragma unroll
  for (int o = 32; o >= 1; o >>= 1) { s += __shfl_xor(s, o); s2 += __shfl_xor(s2, o); }
  float mean = s * (1.f / 512.f);
  float var  = s2 * (1.f / 512.f) - mean * mean;
  float rstd = rsqrtf(var + 1e-5f);
  unsigned short* yp = Y + (size_t)row * DM;
#pragma unroll
  for (int j = 0; j < 8; j++) {
    int c = lane + 64 * j;
    yp[c] = f2bf((v[j] - mean) * rstd * g[c] + b[c]);
  }
}

// =================== fused X += (Hw+1)Y + Hb  ->  LN -> bf16 ===================
__global__ __launch_bounds__(256) void align_ln(
    float* __restrict__ X, const float* __restrict__ Y,
    const float* __restrict__ H,
    const float* __restrict__ g, const float* __restrict__ bb,
    unsigned short* __restrict__ XN)
{
  int wv = threadIdx.x >> 6, lane = threadIdx.x & 63;
  int row = blockIdx.x * 4 + wv;
  int b = row / NN;
  float* xp = X + (size_t)row * DM;
  const float* yp = Y + (size_t)row * DM;
  const float* hw = H + (size_t)b * 1024;
  const float* hb = hw + 512;
  float v[8]; float s = 0.f, s2 = 0.f;
#pragma unroll
  for (int j = 0; j < 8; j++) {
    int c = lane + 64 * j;
    float xv = xp[c] + (hw[c] + 1.f) * yp[c] + hb[c];
    v[j] = xv; s += xv; s2 += xv * xv;
  }
#pragma unroll
  for (int j = 0; j < 8; j++) xp[lane + 64 * j] = v[j];
#pragma unroll
  for (int o = 32; o >= 1; o >>= 1) { s += __shfl_xor(s, o); s2 += __shfl_xor(s2, o); }
  float mean = s * (1.f / 512.f);
  float var  = s2 * (1.f / 512.f) - mean * mean;
  float rstd = rsqrtf(var + 1e-5f);
  unsigned short* yn = XN + (size_t)row * DM;
#pragma unroll
  for (int j = 0; j < 8; j++) {
    int c = lane + 64 * j;
    yn[c] = f2bf((v[j] - mean) * rstd * g[c] + bb[c]);
  }
}

// =================== f32 -> bf16 elementwise (weights / memory) ===================
__global__ __launch_bounds__(256) void cvt_bf16(
    const float* __restrict__ in, unsigned short* __restrict__ out, int n4)
{
  int i = blockIdx.x * 256 + threadIdx.x;
  if (i >= n4) return;
  float4 v = ((const float4*)in)[i];
  union { unsigned short s[4]; uint2 u; } o;
  o.s[0] = f2bf(v.x); o.s[1] = f2bf(v.y); o.s[2] = f2bf(v.z); o.s[3] = f2bf(v.w);
  *(uint2*)&out[(size_t)i * 4] = o.u;
}

// =================== f32 [R,C] -> bf16 [R,Cpad], pad cols zero ===================
__global__ __launch_bounds__(256) void cvt_pad_bf16(
    const float* __restrict__ in, unsigned short* __restrict__ out,
    int R, int C, int Cpad)
{
  int idx = blockIdx.x * 256 + threadIdx.x;
  int r = idx / Cpad, c = idx % Cpad;
  if (r >= R) return;
  out[idx] = (c < C) ? f2bf(in[(size_t)r * C + c]) : (unsigned short)0;
}

// =================== transpose f32 [R,C] -> bf16 [Cpad,R], pad rows zero ===================
__global__ __launch_bounds__(256) void transpose_bf16(
    const float* __restrict__ in, unsigned short* __restrict__ out,
    int R, int Ccols, int Cpad)
{
  __shared__ float t[32][33];
  int c0 = blockIdx.x * 32, r0 = blockIdx.y * 32;
  int x = threadIdx.x & 31, y = threadIdx.x >> 5;   // y in 0..7
#pragma unroll
  for (int dy = 0; dy < 32; dy += 8) {
    int r = r0 + y + dy, c = c0 + x;
    t[y + dy][x] = (r < R && c < Ccols) ? in[(size_t)r * Ccols + c] : 0.f;
  }
  __syncthreads();
#pragma unroll
  for (int dy = 0; dy < 32; dy += 8) {
    int c = c0 + y + dy, r = r0 + x;
    if (c < Cpad && r < R) out[(size_t)c * R + r] = f2bf(t[x][y + dy]);
  }
}

// =================== bf16-input GEMM, m97 structure + dbuf + XCD swizzle ===================
// A bf16 [M,K] k-major, W bf16 [Npad,K] k-major (Npad mult of 128, pad rows zero).
// K must be a multiple of 64 (all call sites: 512/640/2048).
// EPI: 0 f32, 1 f32+bias, 2 bf16 relu(+bias), 3 f32+bias+R,
//      7 bf16+bias head-major QKV planes [sec*8+h][M][64] (uses coloff),
//      8 dual bf16: col<1248 -> Cv [M][1248]; col>=1280 -> R as ushort* [M][640]
template<int EPI>
__global__ __launch_bounds__(256) void gemm_bb(
    const unsigned short* __restrict__ A, int lda,
    const unsigned short* __restrict__ W, int ldw,
    const float* __restrict__ bias,
    const float* __restrict__ R, int ldr,
    void* __restrict__ Cv, int ldc,
    int M, int K, int NC, int coloff)
{
  __shared__ __align__(16) unsigned short As[2][128 * 32];
  __shared__ __align__(16) unsigned short Bs[2][128 * 32];
  const int tid = threadIdx.x;
  const int wave = tid >> 6, lane = tid & 63;
  const int wr = wave >> 1, wc = wave & 1;
  const int quad = lane >> 4, l16 = lane & 15;

  // XCD-aware bijective remap (m204): contiguous tile chunk per XCD.
  const unsigned nx = gridDim.x, nwg = nx * gridDim.y;
  const unsigned orig = blockIdx.y * nx + blockIdx.x;
  const unsigned qq = nwg >> 3, rr = nwg & 7;
  const unsigned xcd = orig & 7, idx = orig >> 3;
  const unsigned swz = (xcd < rr) ? (xcd * (qq + 1) + idx)
                                  : (rr * (qq + 1) + (xcd - rr) * qq + idx);
  const int n0 = (int)(swz % nx) * 128;
  const int m0 = (int)(swz / nx) * 128;

  int ra = m0 + (tid >> 2);
  int ra0 = (ra      >= M) ? M - 1 : ra;
  int ra1 = (ra + 64 >= M) ? M - 1 : ra + 64;
  const unsigned short* a0 = A + (size_t)ra0 * lda + (tid & 3) * 8;
  const unsigned short* a1 = A + (size_t)ra1 * lda + (tid & 3) * 8;
  const unsigned short* b0 = W + (size_t)(n0 + (tid >> 2)) * ldw + (tid & 3) * 8;
  const unsigned short* b1 = b0 + (size_t)64 * ldw;

  f32x4 acc[4][4];
#pragma unroll
  for (int i = 0; i < 4; i++)
#pragma unroll
    for (int j = 0; j < 4; j++) acc[i][j] = (f32x4){0.f, 0.f, 0.f, 0.f};

  auto STAGE = [&](int buf, int k0) {
    gld16(a0 + k0, &As[buf][wave * 512]);
    gld16(a1 + k0, &As[buf][2048 + wave * 512]);
    gld16(b0 + k0, &Bs[buf][wave * 512]);
    gld16(b1 + k0, &Bs[buf][2048 + wave * 512]);
  };
  auto COMPUTE = [&](int buf) {
    short8 af[4], bq[4];
#pragma unroll
    for (int i = 0; i < 4; i++)
      af[i] = *(const short8*)&As[buf][(wr * 64 + i * 16 + l16) * 32 + quad * 8];
#pragma unroll
    for (int j = 0; j < 4; j++)
      bq[j] = *(const short8*)&Bs[buf][(wc * 64 + j * 16 + l16) * 32 + quad * 8];
#pragma unroll
    for (int i = 0; i < 4; i++)
#pragma unroll
      for (int j = 0; j < 4; j++)
        acc[i][j] = __builtin_amdgcn_mfma_f32_16x16x32_bf16(af[i], bq[j], acc[i][j], 0, 0, 0);
  };

  // 2-phase double-buffered pipeline (T3-minimum): loads fly under MFMA.
  STAGE(0, 0);
  __syncthreads();                   // vmcnt(0): buf0 ready
  for (int k0 = 0; k0 < K; k0 += 64) {
    STAGE(1, k0 + 32);               // always valid: k0+32 <= K-32
    COMPUTE(0);
    __syncthreads();                 // buf1 ready; buf0 reads done
    if (k0 + 64 < K) STAGE(0, k0 + 64);
    COMPUTE(1);
    __syncthreads();                 // buf0 ready; buf1 reads done
  }

#pragma unroll
  for (int i = 0; i < 4; i++) {
    int rbase = m0 + wr * 64 + i * 16 + quad * 4;
#pragma unroll
    for (int r = 0; r < 4; r++) {
      int row = rbase + r;
      if (row < M) {
        size_t rowc = (size_t)row * ldc;
#pragma unroll
        for (int j = 0; j < 4; j++) {
          int col = n0 + wc * 64 + j * 16 + l16;
          if (col < NC) {
            float e = acc[i][j][r];
            if (EPI == 1 || EPI == 2 || EPI == 3 || EPI == 7) e += bias[col];
            if (EPI == 3) e += R[(size_t)row * ldr + col];
            if (EPI == 2) {
              ((unsigned short*)Cv)[rowc + col] = f2bf(fmaxf(e, 0.f));
            } else if (EPI == 7) {
              int cc = col + coloff;
              int sec = cc >> 9, hh = (cc >> 6) & 7, dh = cc & 63;
              ((unsigned short*)Cv)[(((size_t)(sec * 8 + hh)) * M + row) * 64 + dh] = f2bf(e);
            } else if (EPI == 8) {
              if (col < 1248)
                ((unsigned short*)Cv)[(size_t)row * 1248 + col] = f2bf(e);
              else if (col >= 1280)
                ((unsigned short*)(void*)R)[(size_t)row * 640 + (col - 1280)] = f2bf(e);
            } else {
              ((float*)Cv)[rowc + col] = e;
            }
          }
        }
      }
    }
  }
}

// =================== ds (kinematic-tree) attention, bf16 COMB + bf16 V ===================
__global__ __launch_bounds__(256) void ds_attn_kernel(
    const unsigned short* __restrict__ COMB, unsigned short* __restrict__ V)
{
  __shared__ float ks[4][2][24][6];
  __shared__ float vs[4][2][24][6];
  int wv = threadIdx.x >> 6, lane = threadIdx.x & 63;
  int half = lane >> 5, i = lane & 31;
  int u  = blockIdx.x * 4 + wv;     // head-pair unit
  int bn = u >> 1, hp = u & 1;
  int h  = hp * 2 + half;
  size_t cbase = (size_t)bn * 1248 + h * 156 + 3;
  size_t vbase = (size_t)bn * 640  + h * 156 + 3;

  float q[6];
  if (i < 24) {
#pragma unroll
    for (int j = 0; j < 6; j++) {
      q[j]                 = bf2f(COMB[cbase + i * 6 + j]);
      ks[wv][half][i][j]   = bf2f(COMB[cbase + 624 + i * 6 + j]);
      vs[wv][half][i][j]   = bf2f(V[vbase + i * 6 + j]);
    }
  } else {
#pragma unroll
    for (int j = 0; j < 6; j++) q[j] = 0.f;
  }
  __syncthreads();

  float p[24];
#pragma unroll
  for (int k = 0; k < 24; k++) p[k] = 0.f;

  if (i < 24) {
    float mx = -1e30f;
#pragma unroll
    for (int k = 0; k < 24; k++) {
      float s = 0.f;
#pragma unroll
      for (int j = 0; j < 6; j++) s += q[j] * ks[wv][half][k][j];
      s *= 0.4082482904638631f;   // 1/sqrt(6)
      p[k] = s; mx = fmaxf(mx, s);
    }
    float sum = 0.f;
#pragma unroll
    for (int k = 0; k < 24; k++) { p[k] = __expf(p[k] - mx); sum += p[k]; }
    float inv = 1.f / sum;
#pragma unroll
    for (int k = 0; k < 24; k++) p[k] *= inv;
  }

  {
    float c = p[0];
    float t;
    t = __shfl(c, 3, 32);  if (i == 6) c = (c + t) * 0.5f;
    t = __shfl(c, 6, 32);  if (i == 9) c = (c + t) * 0.5f;
    t = __shfl(c, 9, 32);  if (i >= 12 && i <= 14) c = (c + t) * 0.5f;
    int src = (i >= 3) ? (i - 3) : 0;
    t = __shfl(c, src, 32); if (i >= 15 && i <= 17) c = (c + t) * 0.5f;
    p[0] = c;
  }
  if (i == 0) {
    p[6]  = (p[6]  + p[3])  * 0.5f;
    p[9]  = (p[9]  + p[6])  * 0.5f;
    p[12] = (p[12] + p[9])  * 0.5f;
    p[13] = (p[13] + p[9])  * 0.5f;
    p[14] = (p[14] + p[9])  * 0.5f;
    p[16] = (p[16] + p[13]) * 0.5f;
    p[17] = (p[17] + p[14]) * 0.5f;
    p[15] = (p[15] + p[12]) * 0.5f;
  }

  if (i < 24) {
    float o[6] = {0.f, 0.f, 0.f, 0.f, 0.f, 0.f};
#pragma unroll
    for (int k = 0; k < 24; k++) {
#pragma unroll
      for (int j = 0; j < 6; j++) o[j] += p[k] * vs[wv][half][k][j];
    }
#pragma unroll
    for (int j = 0; j < 6; j++) V[vbase + i * 6 + j] = f2bf(o[j]);
  }
}

// =================== MFMA MHA, head-major QKV planes [sec*8+h][rowsT][64] ===================
// Q/K staged in LDS (contiguous copies); O via per-wave LDS transpose; setprio
// around MFMA clusters (8 independent waves -> scheduler has roles to arbitrate).
__global__ __launch_bounds__(512) void mha_mfma(
    const unsigned short* __restrict__ QKV3, unsigned short* __restrict__ Op,
    int rowsT, float scale)
{
  __shared__ __align__(16) unsigned short Ksh[304 * 72];
  __shared__ __align__(16) unsigned short Qsh[304 * 72];
  __shared__ __align__(16) unsigned short Vt[64 * 328];
  __shared__ __align__(16) unsigned short Pt[8][16 * 68];
  const int bh = blockIdx.x, b = bh >> 3, h = bh & 7;
  const int tid = threadIdx.x, wv = tid >> 6, lane = tid & 63;
  const int quad = lane >> 4, l16 = lane & 15;
  const unsigned short* Qp = QKV3 + ((size_t)h        * rowsT + b * NN) * 64;
  const unsigned short* Kp = QKV3 + ((size_t)(8 + h)  * rowsT + b * NN) * 64;
  const unsigned short* Vp = QKV3 + ((size_t)(16 + h) * rowsT + b * NN) * 64;

  // ---- stage K and Q: contiguous [300][64] -> [304][72] (rows 300..303 zero) ----
  for (int f = tid; f < 304 * 8; f += 512) {
    int rk = f >> 3, c8 = (f & 7) * 8;
    short8 wk, wq;
    if (rk < 300) {
      wk = *(const short8*)(Kp + f * 8);          // rk*64 + c8 == f*8
      wq = *(const short8*)(Qp + f * 8);
    } else {
      union { uint4 u; short8 s; } z; z.u = make_uint4(0u, 0u, 0u, 0u);
      wk = z.s; wq = z.s;
    }
    *(short8*)&Ksh[rk * 72 + c8] = wk;
    *(short8*)&Qsh[rk * 72 + c8] = wq;
  }
  // ---- stage V^T: Vt[d][seq], seq >= 300 zeroed ----
  for (int f = tid; f < 64 * 164; f += 512) {
    int d = f & 63, s0 = (f >> 6) * 2;
    unsigned w = 0u;
    if (s0 < 300) {
      unsigned short v0 = Vp[s0 * 64 + d];
      unsigned short v1 = (s0 + 1 < 300) ? Vp[(s0 + 1) * 64 + d] : (unsigned short)0;
      w = (unsigned)v0 | ((unsigned)v1 << 16);
    }
    *(unsigned*)&Vt[d * 328 + s0] = w;
  }
  __syncthreads();

  unsigned short* pt = &Pt[wv][0];

  for (int qt = wv; qt < 19; qt += 8) {
    int qr = qt * 16 + l16;                       // 0..303; pad rows are zero
    short8 qf[2];
    qf[0] = *(const short8*)&Qsh[qr * 72 + quad * 8];
    qf[1] = *(const short8*)&Qsh[qr * 72 + 32 + quad * 8];

    // S' = K Q^T: rows = seq (19 tiles of 16), cols = qrow
    f32x4 sacc[19];
    __builtin_amdgcn_s_setprio(1);
#pragma unroll
    for (int t = 0; t < 19; t++) {
      short8 k0 = *(const short8*)&Ksh[(t * 16 + l16) * 72 + quad * 8];
      short8 k1 = *(const short8*)&Ksh[(t * 16 + l16) * 72 + 32 + quad * 8];
      f32x4 a = (f32x4){0.f, 0.f, 0.f, 0.f};
      a = __builtin_amdgcn_mfma_f32_16x16x32_bf16(k0, qf[0], a, 0, 0, 0);
      a = __builtin_amdgcn_mfma_f32_16x16x32_bf16(k1, qf[1], a, 0, 0, 0);
      sacc[t] = a;
    }
    __builtin_amdgcn_s_setprio(0);

    // softmax over seq for qrow = l16: in-lane over (t,r), cross-quad shfl
    float mx = -1e30f;
#pragma unroll
    for (int t = 0; t < 19; t++)
#pragma unroll
      for (int r = 0; r < 4; r++) mx = fmaxf(mx, sacc[t][r]);
    mx = fmaxf(mx, __shfl_xor(mx, 16));
    mx = fmaxf(mx, __shfl_xor(mx, 32));
    float sum = 0.f;
#pragma unroll
    for (int t = 0; t < 19; t++) {
#pragma unroll
      for (int r = 0; r < 4; r++) {
        float p = __expf((sacc[t][r] - mx) * scale);
        if (t == 18 && quad == 3) p = 0.f;     // seq 300..303 pad
        sacc[t][r] = p; sum += p;
      }
    }
    sum += __shfl_xor(sum, 16);
    sum += __shfl_xor(sum, 32);
    float inv = 1.f / sum;

    // PV: O[qrow][d] = sum_seq P[seq][qrow] V[seq][d]
    f32x4 oacc[4];
#pragma unroll
    for (int dt = 0; dt < 4; dt++) oacc[dt] = (f32x4){0.f, 0.f, 0.f, 0.f};
#pragma unroll
    for (int c = 0; c < 10; c++) {
#pragma unroll
      for (int tic = 0; tic < 2; tic++) {
        int t = 2 * c + tic;
        unsigned w0 = 0u, w1 = 0u;
        if (t < 19) {
          w0 = pack_trunc(sacc[t][0], sacc[t][1]);
          w1 = pack_trunc(sacc[t][2], sacc[t][3]);
        }
        *(unsigned*)&pt[l16 * 68 + tic * 16 + quad * 4]     = w0;
        *(unsigned*)&pt[l16 * 68 + tic * 16 + quad * 4 + 2] = w1;
      }
      short8 pa = *(const short8*)&pt[l16 * 68 + quad * 8];
      __builtin_amdgcn_s_setprio(1);
#pragma unroll
      for (int dt = 0; dt < 4; dt++) {
        short8 vb = *(const short8*)&Vt[(dt * 16 + l16) * 328 + c * 32 + quad * 8];
        oacc[dt] = __builtin_amdgcn_mfma_f32_16x16x32_bf16(pa, vb, oacc[dt], 0, 0, 0);
      }
      __builtin_amdgcn_s_setprio(0);
    }

    // epilogue: transpose through Pt, then 16B/lane contiguous stores
#pragma unroll
    for (int r = 0; r < 4; r++) {
      float iv = __shfl(inv, quad * 4 + r);
#pragma unroll
      for (int dt = 0; dt < 4; dt++)
        pt[(quad * 4 + r) * 68 + dt * 16 + l16] = f2bf(oacc[dt][r] * iv);
    }
#pragma unroll
    for (int rep = 0; rep < 2; rep++) {
      int idx = rep * 64 + lane;
      int rl = idx >> 3, seg = idx & 7;
      int row = qt * 16 + rl;
      uint4 w = *(const uint4*)&pt[rl * 68 + seg * 8];
      if (row < 300)
        *(uint4*)(Op + (size_t)(b * NN + row) * DM + h * 64 + seg * 8) = w;
    }
  }
}

// =================== column mean over seq + mish(t + mean) -> bf16 ===================
__global__ __launch_bounds__(256) void colmean_mish(
    const float* __restrict__ Y, const float* __restrict__ tvec,
    unsigned short* __restrict__ mm)
{
  int g = blockIdx.x * 256 + threadIdx.x;
  int b = g >> 9, d = g & 511;
  const float* yp = Y + (size_t)b * NN * DM + d;
  float s = 0.f;
  for (int n = 0; n < NN; n++) s += yp[(size_t)n * DM];
  float v = tvec[g] + s * (1.f / 300.f);
  float sp = (v > 20.f) ? v : log1pf(__expf(v));
  mm[g] = f2bf(v * tanhf(sp));
}

// =================== X += (Hw+1)*Y + Hb ===================
__global__ __launch_bounds__(256) void align_apply(
    float* __restrict__ X, const float* __restrict__ Y,
    const float* __restrict__ H)
{
  int idx = blockIdx.x * 256 + threadIdx.x;  // rows*128 float4s
  int row = idx >> 7;
  int d4  = (idx & 127) * 4;
  int b   = row / NN;
  float4 y = *(const float4*)&Y[(size_t)row * DM + d4];
  float4 x = *(const float4*)&X[(size_t)row * DM + d4];
  const float* hw = H + (size_t)b * 1024 + d4;
  const float* hb = hw + 512;
  x.x += (hw[0] + 1.f) * y.x + hb[0];
  x.y += (hw[1] + 1.f) * y.y + hb[1];
  x.z += (hw[2] + 1.f) * y.z + hb[2];
  x.w += (hw[3] + 1.f) * y.w + hb[3];
  *(float4*)&X[(size_t)row * DM + d4] = x;
}

// =================== launch ===================
extern "C" void kernel_launch(void* const* d_in, const int* in_sizes, int n_in,
                              void* d_out, int out_size, void* d_ws, size_t ws_size,
                              hipStream_t stream)
{
  const float* tgt      = (const float*)d_in[0];
  const float* memory   = (const float*)d_in[1];
  const float* tvec     = (const float*)d_in[2];
  const float* qk_w     = (const float*)d_in[3];
  const float* v_w      = (const float*)d_in[4];
  const float* ds_lw    = (const float*)d_in[5];
  const float* ds_lb    = (const float*)d_in[6];
  const float* ta_in_w  = (const float*)d_in[7];
  const float* ta_in_b  = (const float*)d_in[8];
  const float* ta_out_w = (const float*)d_in[9];
  const float* ta_out_b = (const float*)d_in[10];
  const float* ca_in_w  = (const float*)d_in[11];
  const float* ca_in_b  = (const float*)d_in[12];
  const float* ca_out_w = (const float*)d_in[13];
  const float* ca_out_b = (const float*)d_in[14];
  const float* l1_w     = (const float*)d_in[15];
  const float* l1_b     = (const float*)d_in[16];
  const float* l2_w     = (const float*)d_in[17];
  const float* l2_b     = (const float*)d_in[18];
  const float* n1_g = (const float*)d_in[19]; const float* n1_b = (const float*)d_in[20];
  const float* n2_g = (const float*)d_in[21]; const float* n2_b = (const float*)d_in[22];
  const float* n3_g = (const float*)d_in[23]; const float* n3_b = (const float*)d_in[24];
  const float* n4_g = (const float*)d_in[25]; const float* n4_b = (const float*)d_in[26];
  const float* a1_w = (const float*)d_in[27]; const float* a1_b = (const float*)d_in[28];
  const float* a2_w = (const float*)d_in[29]; const float* a2_b = (const float*)d_in[30];
  const float* a3_w = (const float*)d_in[31]; const float* a3_b = (const float*)d_in[32];

  // ---- fixed workspace (bytes): bf16 weight copies ----
  const size_t W_W2  = 1920ULL * 512 * 2;    // merged qk^T (1280) + v^T (640)
  const size_t W_TAI = 1536ULL * 512 * 2;
  const size_t W_TAO = 512ULL  * 512 * 2;
  const size_t W_CAI = 1536ULL * 512 * 2;
  const size_t W_CAO = 512ULL  * 512 * 2;
  const size_t W_L1  = 2048ULL * 512 * 2;
  const size_t W_L2  = 512ULL  * 2048 * 2;
  const size_t W_DSL = 512ULL  * 640 * 2;
  const size_t W_AX  = 1024ULL * 512 * 2;    // x3
  const size_t W_MEM = (size_t)BB * NN * 512 * 2;
  const size_t fixedB = W_W2 + W_TAI + W_TAO + W_CAI + W_CAO
                      + W_L1 + W_L2 + W_DSL + 3 * W_AX + W_MEM;
  // per-batch: XNh bf16[300][512] + SCRB 300x4096B (COMB bf16 1248 / QKV3 planes
  // 1536x2B / FFN bf16 2048) + Vdsh bf16[300][640] + Yb f32[300][512] + MMh + Hb
  const size_t per_b = 300ULL * (1024 + 4096 + 1280 + 2048) + 1024 + 4096;  // 2,539,520
  int Bc = 128;
  while (Bc > 16 && fixedB + (size_t)Bc * per_b > ws_size) Bc >>= 1;
  const int rows = Bc * NN;
  const int mB   = (rows + 127) / 128;
  const int aB   = (Bc + 127) / 128;
  const int nchunks = BB / Bc;

  char* p = (char*)d_ws;
  unsigned short* W2h   = (unsigned short*)p; p += W_W2;
  unsigned short* taiWh = (unsigned short*)p; p += W_TAI;
  unsigned short* taoWh = (unsigned short*)p; p += W_TAO;
  unsigned short* caiWh = (unsigned short*)p; p += W_CAI;
  unsigned short* caoWh = (unsigned short*)p; p += W_CAO;
  unsigned short* l1Wh  = (unsigned short*)p; p += W_L1;
  unsigned short* l2Wh  = (unsigned short*)p; p += W_L2;
  unsigned short* dslWh = (unsigned short*)p; p += W_DSL;
  unsigned short* a1Wh  = (unsigned short*)p; p += W_AX;
  unsigned short* a2Wh  = (unsigned short*)p; p += W_AX;
  unsigned short* a3Wh  = (unsigned short*)p; p += W_AX;
  unsigned short* memh  = (unsigned short*)p; p += W_MEM;
  unsigned short* XNh   = (unsigned short*)p; p += (size_t)rows * 512 * 2;
  char* SCRB = p;                             p += (size_t)rows * 4096;
  unsigned short* Vdsh  = (unsigned short*)p; p += (size_t)rows * 640 * 2;
  float* Yb  = (float*)p; p += (size_t)rows * 512 * 4;
  unsigned short* MMh = (unsigned short*)p;   p += (size_t)Bc * 512 * 2;
  float* Hb  = (float*)p;

  unsigned short* COMBh = (unsigned short*)SCRB; // [rows][1248] bf16
  unsigned short* QKV3  = (unsigned short*)SCRB; // [24][rows][64] bf16 planes
  unsigned short* T2h   = (unsigned short*)SCRB; // [rows][2048] bf16

  dim3 thr(256);

  // ---- one-time weight / memory conversion ----
  transpose_bf16<<<dim3(40, 16), thr, 0, stream>>>(qk_w, W2h, 512, 1248, 1280);
  transpose_bf16<<<dim3(20, 16), thr, 0, stream>>>(v_w,  W2h + 1280 * 512, 512, 624, 640);
  cvt_pad_bf16<<<dim3(512 * 640 / 256), thr, 0, stream>>>(ds_lw, dslWh, 512, 624, 640);
  auto cvt = [&](const float* src, unsigned short* dst, size_t n) {
    int n4 = (int)(n / 4);
    cvt_bf16<<<dim3((n4 + 255) / 256), thr, 0, stream>>>(src, dst, n4);
  };
  cvt(ta_in_w,  taiWh, 1536ULL * 512);
  cvt(ta_out_w, taoWh, 512ULL * 512);
  cvt(ca_in_w,  caiWh, 1536ULL * 512);
  cvt(ca_out_w, caoWh, 512ULL * 512);
  cvt(l1_w,     l1Wh,  2048ULL * 512);
  cvt(l2_w,     l2Wh,  512ULL * 2048);
  cvt(a1_w,     a1Wh,  1024ULL * 512);
  cvt(a2_w,     a2Wh,  1024ULL * 512);
  cvt(a3_w,     a3Wh,  1024ULL * 512);
  cvt(memory,   memh,  (size_t)BB * NN * 512);

  for (int c = 0; c < nchunks; ++c) {
    const size_t roff = (size_t)c * Bc * NN * DM;
    const float* tgtC = tgt    + roff;
    const float* tC   = tvec   + (size_t)c * Bc * 512;
    const unsigned short* memhC = memh + roff;
    float*       XC   = (float*)d_out + roff;

    // ---- ds-attention branch: x = tgt + ds_attn(LN1(tgt)) ----
    ln_kernel<<<rows / 4, thr, 0, stream>>>(tgtC, n1_g, n1_b, XNh, rows);
    gemm_bb<8><<<dim3(15, mB), thr, 0, stream>>>(XNh, 512, W2h, 512, nullptr, (const float*)Vdsh, 0, COMBh, 1248, rows, 512, 1920, 0);
    ds_attn_kernel<<<rows / 2, thr, 0, stream>>>(COMBh, Vdsh);
    gemm_bb<3><<<dim3(4, mB),  thr, 0, stream>>>(Vdsh, 640, dslWh, 640, ds_lb, tgtC, 512, XC, 512, rows, 640, 512, 0);

    // ---- self attention + align1 (+fused LN3) ----
    ln_kernel<<<rows / 4, thr, 0, stream>>>(XC, n2_g, n2_b, XNh, rows);
    gemm_bb<7><<<dim3(12, mB), thr, 0, stream>>>(XNh, 512, taiWh, 512, ta_in_b, nullptr, 0, QKV3, 0, rows, 512, 1536, 0);
    mha_mfma<<<Bc * 8, 512, 0, stream>>>(QKV3, XNh, rows, 0.125f);
    gemm_bb<1><<<dim3(4, mB),  thr, 0, stream>>>(XNh, 512, taoWh, 512, ta_out_b, nullptr, 0, Yb, 512, rows, 512, 512, 0);
    colmean_mish<<<Bc * 2, thr, 0, stream>>>(Yb, tC, MMh);
    gemm_bb<1><<<dim3(8, aB),  thr, 0, stream>>>(MMh, 512, a1Wh, 512, a1_b, nullptr, 0, Hb, 1024, Bc, 512, 1024, 0);
    align_ln<<<rows / 4, thr, 0, stream>>>(XC, Yb, Hb, n3_g, n3_b, XNh);

    // ---- cross attention + align2 (+fused LN4) ----
    gemm_bb<7><<<dim3(4, mB),  thr, 0, stream>>>(XNh, 512, caiWh, 512, ca_in_b, nullptr, 0, QKV3, 0, rows, 512, 512, 0);
    gemm_bb<7><<<dim3(8, mB),  thr, 0, stream>>>(memhC, 512, caiWh + 512 * 512, 512, ca_in_b + 512, nullptr, 0, QKV3, 0, rows, 512, 1024, 512);
    mha_mfma<<<Bc * 8, 512, 0, stream>>>(QKV3, XNh, rows, 0.125f);
    gemm_bb<1><<<dim3(4, mB),  thr, 0, stream>>>(XNh, 512, caoWh, 512, ca_out_b, nullptr, 0, Yb, 512, rows, 512, 512, 0);
    colmean_mish<<<Bc * 2, thr, 0, stream>>>(Yb, tC, MMh);
    gemm_bb<1><<<dim3(8, aB),  thr, 0, stream>>>(MMh, 512, a2Wh, 512, a2_b, nullptr, 0, Hb, 1024, Bc, 512, 1024, 0);
    align_ln<<<rows / 4, thr, 0, stream>>>(XC, Yb, Hb, n4_g, n4_b, XNh);

    // ---- FFN (merged N=2048, K=2048) + align3 ----
    gemm_bb<2><<<dim3(16, mB), thr, 0, stream>>>(XNh, 512, l1Wh, 512, l1_b, nullptr, 0, T2h, 2048, rows, 512, 2048, 0);
    gemm_bb<1><<<dim3(4, mB),  thr, 0, stream>>>(T2h, 2048, l2Wh, 2048, l2_b, nullptr, 0, Yb, 512, rows, 2048, 512, 0);
    colmean_mish<<<Bc * 2, thr, 0, stream>>>(Yb, tC, MMh);
    gemm_bb<1><<<dim3(8, aB),  thr, 0, stream>>>(MMh, 512, a3Wh, 512, a3_b, nullptr, 0, Hb, 1024, Bc, 512, 1024, 0);
    align_apply<<<rows / 2, thr, 0, stream>>>(XC, Yb, Hb);
  }
}